// Round 9
// baseline (456.219 us; speedup 1.0000x reference)
//
#include <hip/hip_runtime.h>
#include <hip/hip_bf16.h>

#define NPTS    100000
#define KCENT   1024
#define NSEG    391          // ceil(NPTS/256)
#define NWORDS  1564         // NSEG*4 words of 64 points
#define WSTRIDE 1600         // mask words per centroid (padded)
#define MB_BLKS (NSEG*32)    // 12512 maskbuild blocks

typedef __attribute__((ext_vector_type(8))) short bf16x8;   // 8 bf16 (4 VGPRs)
typedef __attribute__((ext_vector_type(4))) float f32x4;
typedef unsigned long long u64;

__device__ __forceinline__ unsigned short f2bf(float x) {
  union { float f; unsigned u; } v; v.f = x;
  unsigned r = v.u + 0x7FFFu + ((v.u >> 16) & 1u);   // RNE
  return (unsigned short)(r >> 16);
}
__device__ __forceinline__ unsigned pk2bf(float a, float b) {
  union { __hip_bfloat162 h; unsigned u; } cv;
  cv.h = __float22bfloat162_rn(make_float2(a, b));
  return cv.u;
}
__device__ __forceinline__ bf16x8 pack_bf8(f32x4 a, f32x4 b) {
  union { bf16x8 v; unsigned u[4]; } r;
  r.u[0] = pk2bf(a[0], a[1]); r.u[1] = pk2bf(a[2], a[3]);
  r.u[2] = pk2bf(b[0], b[1]); r.u[3] = pk2bf(b[2], b[3]);
  return r.v;
}

// ---------------------------------------------------------------- maskbuild + prep (fused, independent halves)
// blocks [0, MB_BLKS): ball mask via ballot, 32 centroids x 256 points/block
//   (R6-proven variant). maskbuf[centroid*WSTRIDE + word].
// blocks [MB_BLKS, ...): prep — featsBF bf16, coords4, W1T(stride 104,
//   augmented: k<64 feat rows, 64..66 rel rows, 67 b1, rest 0), W2T/W3T(72),
//   cent gather -> d_out[0:3072).
__global__ __launch_bounds__(256) void build_prep_kernel(
    const float* __restrict__ coords, const float* __restrict__ features,
    const int* __restrict__ cidx, const float* __restrict__ W1,
    const float* __restrict__ b1, const float* __restrict__ W2,
    const float* __restrict__ W3, u64* __restrict__ maskbuf,
    unsigned short* __restrict__ featsBF, f32x4* __restrict__ coords4,
    unsigned short* __restrict__ W1T, unsigned short* __restrict__ W2T,
    unsigned short* __restrict__ W3T, float* __restrict__ outCent) {
  const int bid = blockIdx.x;
  const int tid = threadIdx.x;
  if (bid < MB_BLKS) {
    const int grp = bid / NSEG, seg = bid - grp*NSEG;
    __shared__ float sC[96];
    __shared__ float sCC[32];
    if (tid < 96) sC[tid] = coords[cidx[grp*32 + tid/3]*3 + tid%3];
    __syncthreads();
    if (tid < 32) {
      float x = sC[tid*3], y = sC[tid*3+1], z = sC[tid*3+2];
      sCC[tid] = __fadd_rn(__fadd_rn(__fmul_rn(x,x), __fmul_rn(y,y)), __fmul_rn(z,z));
    }
    const int p = seg*256 + tid;
    const bool inr = p < NPTS;
    float px = 0.f, py = 0.f, pz = 0.f;
    if (inr) { px = coords[p*3]; py = coords[p*3+1]; pz = coords[p*3+2]; }
    const float pp = __fadd_rn(__fadd_rn(__fmul_rn(px,px), __fmul_rn(py,py)), __fmul_rn(pz,pz));
    __syncthreads();
    const int lane = tid & 63, wid = tid >> 6;
    u64 myw = 0ull;
    #pragma unroll
    for (int ci = 0; ci < 32; ++ci) {
      float cx = sC[ci*3], cy = sC[ci*3+1], cz = sC[ci*3+2];
      float dt = __fadd_rn(__fadd_rn(__fmul_rn(cx,px), __fmul_rn(cy,py)), __fmul_rn(cz,pz));
      float d2 = __fsub_rn(__fadd_rn(sCC[ci], pp), __fmul_rn(2.0f, dt));
      bool sel = inr && (d2 <= 0.04f);
      u64 m = __ballot(sel);
      if (lane == ci) myw = m;
    }
    if (lane < 32)
      maskbuf[(u64)(grp*32 + lane)*WSTRIDE + seg*4 + wid] = myw;
    return;
  }
  int i = (bid - MB_BLKS) * 256 + tid;
  if (i < 800000) {                       // 8 feature floats -> bf16x8
    const f32x4* src = (const f32x4*)features + i*2;
    f32x4 f0 = src[0], f1 = src[1];
    union { bf16x8 v; uint4 u; } pk; pk.v = pack_bf8(f0, f1);
    ((uint4*)featsBF)[i] = pk.u;
    return;
  }
  i -= 800000;
  if (i < NPTS) {
    coords4[i] = (f32x4){coords[3*i], coords[3*i+1], coords[3*i+2], 0.f};
    return;
  }
  i -= NPTS;
  if (i < 6656) {                         // W1T augmented, stride 104
    int n = i / 104, kk = i - n*104;
    float v = 0.f;
    if (kk < 64)       v = W1[(3+kk)*64 + n];
    else if (kk < 67)  v = W1[(kk-64)*64 + n];
    else if (kk == 67) v = b1[n];
    W1T[n*104 + kk] = f2bf(v);
    return;
  }
  i -= 6656;
  if (i < 4608) { int n = i / 72, kk = i - n*72;
    W2T[n*72 + kk] = f2bf(kk < 64 ? W2[kk*64 + n] : 0.f); return; }
  i -= 4608;
  if (i < 9216) { int n = i / 72, kk = i - n*72;
    W3T[n*72 + kk] = f2bf(kk < 64 ? W3[kk*128 + n] : 0.f); return; }
  i -= 9216;
  if (i < KCENT) {
    int ci = cidx[i];
    outCent[i*3+0] = coords[ci*3+0];
    outCent[i*3+1] = coords[ci*3+1];
    outCent[i*3+2] = coords[ci*3+2];
  }
}

// ---------------------------------------------------------------- mega-fused: scan + MLP + maxpool + epilogue
// One 512-thread block (8 waves) per centroid, 4 waves/SIMD occupancy target.
// ALL weights staged in LDS (W1 stride 104, W2/W3 stride 72 — 2-way max bank
// aliasing, free). Single 16-point column per wave per iteration; concurrency
// comes from 4 waves/SIMD instead of in-wave dual columns (register budget:
// ~75 arch + ~48 acc <= 128/wave). Phase 1: 512-thread mask scan — one round
// covers 32768 points, most blocks exit after a single round. Phase 3:
// 8-wave max-pool, +b3, relu.
__global__ __launch_bounds__(512, 4) void fused_kernel(
    const u64* __restrict__ maskbuf, const unsigned short* __restrict__ featsBF,
    const f32x4* __restrict__ coords4, const float* __restrict__ cent,
    const float* __restrict__ b2v, const float* __restrict__ b3v,
    const unsigned short* __restrict__ gW1T, const unsigned short* __restrict__ gW2T,
    const unsigned short* __restrict__ gW3T, float* __restrict__ outF) {
  __shared__ __align__(16) unsigned short sW1T[64*104];   // 13312 B
  __shared__ __align__(16) unsigned short sW2T[64*72];    //  9216 B
  __shared__ __align__(16) unsigned short sW3T[128*72];   // 18432 B
  __shared__ __align__(16) unsigned short sH[8*16*72];    //  9216 B (1152 B/wave)
  __shared__ int sIdx[KCENT];                             //  4096 B
  __shared__ int sTot[8];
  __shared__ float sB2[64], sB3[128];
  __shared__ float sMax[8*128];                           //  4096 B

  const int k = blockIdx.x;
  const int tid = threadIdx.x;
  const int w = tid >> 6, lane = tid & 63;
  const int q = lane >> 4, cl = lane & 15;

  // mask preloads issue first (cover scan rounds 0..2)
  const u64* M = maskbuf + (u64)k * WSTRIDE;
  u64 wv0 = M[tid];
  u64 wv1 = (512  + tid < NWORDS) ? M[512  + tid] : 0ull;
  u64 wv2 = (1024 + tid < NWORDS) ? M[1024 + tid] : 0ull;

  // stage all weights into LDS (coalesced uint4)
  for (int i = tid; i < 832;  i += 512) ((uint4*)sW1T)[i] = ((const uint4*)gW1T)[i];
  for (int i = tid; i < 576;  i += 512) ((uint4*)sW2T)[i] = ((const uint4*)gW2T)[i];
  for (int i = tid; i < 1152; i += 512) ((uint4*)sW3T)[i] = ((const uint4*)gW3T)[i];
  if (tid < 64)  sB2[tid] = b2v[tid];
  if (tid >= 64 && tid < 192) sB3[tid-64] = b3v[tid-64];

  const float cx = cent[k*3], cy = cent[k*3+1], cz = cent[k*3+2];

  // ---- phase 1: ordered compaction into sIdx (8-wave block scan) ----
  int base = 0;
  #pragma unroll 1
  for (int r = 0; r < 4; ++r) {
    const int widx = r*512 + tid;
    u64 word = (r == 0) ? wv0 : (r == 1) ? wv1 : (r == 2) ? wv2
             : ((widx < NWORDS) ? M[widx] : 0ull);
    int pc = __popcll(word);
    int inc = pc;                      // wave-inclusive scan
    #pragma unroll
    for (int d = 1; d < 64; d <<= 1) {
      int t = __shfl_up(inc, d);
      if (lane >= d) inc += t;
    }
    if (lane == 63) sTot[w] = inc;
    __syncthreads();
    int wbase = 0, tot = 0;
    #pragma unroll
    for (int i = 0; i < 8; ++i) { int v = sTot[i]; tot += v; if (i < w) wbase += v; }
    int pos = base + wbase + inc - pc;
    const int pbase = widx * 64;
    while (word != 0ull && pos < KCENT) {
      int b = __ffsll(word) - 1;
      sIdx[pos++] = pbase + b;
      word &= word - 1ull;
    }
    base += tot;
    __syncthreads();                   // sIdx visible + sTot reusable (also covers weight staging)
    if (base >= KCENT) break;          // uniform
  }
  const int count = base < KCENT ? base : KCENT;   // uniform across block

  unsigned short* myH = sH + w*1152;   // 16x72 shorts, wave-private

  f32x4 runmax[8];
  #pragma unroll
  for (int i = 0; i < 8; ++i)
    runmax[i] = (f32x4){-__builtin_inff(), -__builtin_inff(),
                        -__builtin_inff(), -__builtin_inff()};

  // ---- phase 2: MLP, one 16-point column per wave-iteration ----
  const int nstrips = (count + 15) >> 4;
  int s = w;

  int pC = 0;
  { int j = 16*s + cl; if (j < count) pC = sIdx[j]; }
  f32x4  c4 = coords4[pC];
  bf16x8 xf0 = *(const bf16x8*)(featsBF + pC*64 + q*8);
  bf16x8 xf1 = *(const bf16x8*)(featsBF + pC*64 + 32 + q*8);
  int pN = 0;
  { int j = 16*(s+8) + cl; if (j < count) pN = sIdx[j]; }

  const bf16x8 zero8 = (bf16x8){0,0,0,0,0,0,0,0};

  for (; s < nstrips; s += 8) {
    // idx (LDS) two strips ahead
    int pNN = 0;
    { int j = 16*(s+16) + cl; if (j < count) pNN = sIdx[j]; }

    // rel/bias B-fragment (k=64..67: rx,ry,rz,1)
    union { bf16x8 v; unsigned u[4]; } rf;
    rf.u[0] = pk2bf(c4[0]-cx, c4[1]-cy); rf.u[1] = pk2bf(c4[2]-cz, 1.0f);
    rf.u[2] = 0u; rf.u[3] = 0u;
    bf16x8 x2 = (q == 0) ? rf.v : zero8;

    // ---- layer 1 (K=96, rel+bias folded; W1 frags from LDS) ----
    {
      f32x4 acc[4];
      #pragma unroll
      for (int nt = 0; nt < 4; ++nt) acc[nt] = (f32x4){0.f,0.f,0.f,0.f};
      #pragma unroll
      for (int nt = 0; nt < 4; ++nt) {
        const unsigned short* wrow = sW1T + (nt*16+cl)*104 + q*8;
        bf16x8 wa0 = *(const bf16x8*)(wrow);
        acc[nt] = __builtin_amdgcn_mfma_f32_16x16x32_bf16(wa0, xf0, acc[nt], 0,0,0);
        bf16x8 wa1 = *(const bf16x8*)(wrow + 32);
        acc[nt] = __builtin_amdgcn_mfma_f32_16x16x32_bf16(wa1, xf1, acc[nt], 0,0,0);
        bf16x8 wa2 = *(const bf16x8*)(wrow + 64);
        acc[nt] = __builtin_amdgcn_mfma_f32_16x16x32_bf16(wa2, x2,  acc[nt], 0,0,0);
      }
      #pragma unroll
      for (int nt = 0; nt < 4; ++nt) {
        const int o = nt*16 + q*4;
        uint2 pk = { pk2bf(fmaxf(acc[nt][0],0.f), fmaxf(acc[nt][1],0.f)),
                     pk2bf(fmaxf(acc[nt][2],0.f), fmaxf(acc[nt][3],0.f)) };
        *(uint2*)(myH + cl*72 + o) = pk;
      }
    }

    // current xf/c4 dead: issue next strip's data loads
    c4 = coords4[pN];
    xf0 = *(const bf16x8*)(featsBF + pN*64 + q*8);
    xf1 = *(const bf16x8*)(featsBF + pN*64 + 32 + q*8);

    // ---- layer 2 (W2 frags from LDS) ----
    {
      bf16x8 h0 = *(const bf16x8*)(myH + cl*72 + q*8);
      bf16x8 h1 = *(const bf16x8*)(myH + cl*72 + 32 + q*8);
      f32x4 acc[4];
      #pragma unroll
      for (int nt = 0; nt < 4; ++nt) acc[nt] = (f32x4){0.f,0.f,0.f,0.f};
      #pragma unroll
      for (int nt = 0; nt < 4; ++nt) {
        const unsigned short* wrow = sW2T + (nt*16+cl)*72 + q*8;
        bf16x8 wa0 = *(const bf16x8*)(wrow);
        acc[nt] = __builtin_amdgcn_mfma_f32_16x16x32_bf16(wa0, h0, acc[nt], 0,0,0);
        bf16x8 wa1 = *(const bf16x8*)(wrow + 32);
        acc[nt] = __builtin_amdgcn_mfma_f32_16x16x32_bf16(wa1, h1, acc[nt], 0,0,0);
      }
      #pragma unroll
      for (int nt = 0; nt < 4; ++nt) {
        const int o = nt*16 + q*4;
        f32x4 bb = *(const f32x4*)(sB2 + o);
        uint2 pk = { pk2bf(fmaxf(acc[nt][0]+bb[0],0.f), fmaxf(acc[nt][1]+bb[1],0.f)),
                     pk2bf(fmaxf(acc[nt][2]+bb[2],0.f), fmaxf(acc[nt][3]+bb[3],0.f)) };
        *(uint2*)(myH + cl*72 + o) = pk;
      }
    }

    // ---- layer 3 (W3 frags from LDS, nt-quarters) + masked maxpool ----
    {
      bf16x8 h0 = *(const bf16x8*)(myH + cl*72 + q*8);
      bf16x8 h1 = *(const bf16x8*)(myH + cl*72 + 32 + q*8);
      const float vm = (16*s + cl < count) ? 0.f : -__builtin_inff();
      #pragma unroll
      for (int ntq = 0; ntq < 4; ++ntq) {
        f32x4 a3[2];
        #pragma unroll
        for (int j = 0; j < 2; ++j) a3[j] = (f32x4){0.f,0.f,0.f,0.f};
        #pragma unroll
        for (int j = 0; j < 2; ++j) {
          const int nt = ntq*2 + j;
          const unsigned short* wrow = sW3T + (nt*16+cl)*72 + q*8;
          bf16x8 w30 = *(const bf16x8*)(wrow);
          a3[j] = __builtin_amdgcn_mfma_f32_16x16x32_bf16(w30, h0, a3[j], 0,0,0);
          bf16x8 w31 = *(const bf16x8*)(wrow + 32);
          a3[j] = __builtin_amdgcn_mfma_f32_16x16x32_bf16(w31, h1, a3[j], 0,0,0);
        }
        #pragma unroll
        for (int j = 0; j < 2; ++j) {
          const int nt = ntq*2 + j;
          #pragma unroll
          for (int r = 0; r < 4; ++r)
            runmax[nt][r] = fmaxf(runmax[nt][r], a3[j][r] + vm);
        }
      }
    }

    pN = pNN;
  }

  // ---- phase 3: reduce over points (cl), across 8 waves, +b3, relu ----
  #pragma unroll
  for (int nt = 0; nt < 8; ++nt) {
    #pragma unroll
    for (int r = 0; r < 4; ++r) {
      float m = runmax[nt][r];
      m = fmaxf(m, __shfl_xor(m, 1));
      m = fmaxf(m, __shfl_xor(m, 2));
      m = fmaxf(m, __shfl_xor(m, 4));
      m = fmaxf(m, __shfl_xor(m, 8));
      runmax[nt][r] = m;
    }
    if (cl == 0) *(f32x4*)(sMax + w*128 + nt*16 + q*4) = runmax[nt];
  }
  __syncthreads();
  if (tid < 128) {
    float m = sMax[tid];
    #pragma unroll
    for (int i = 1; i < 8; ++i) m = fmaxf(m, sMax[i*128 + tid]);
    outF[k*128 + tid] = fmaxf(m + sB3[tid], 0.f);
  }
}

// ---------------------------------------------------------------- launch
extern "C" void kernel_launch(void* const* d_in, const int* in_sizes, int n_in,
                              void* d_out, int out_size, void* d_ws, size_t ws_size,
                              hipStream_t stream) {
  const float* coords   = (const float*)d_in[0];
  const float* features = (const float*)d_in[1];
  const int*   cidx     = (const int*)d_in[2];
  const float* W1 = (const float*)d_in[3];
  const float* b1 = (const float*)d_in[4];
  const float* W2 = (const float*)d_in[5];
  const float* b2 = (const float*)d_in[6];
  const float* W3 = (const float*)d_in[7];
  const float* b3 = (const float*)d_in[8];
  float* out = (float*)d_out;           // [0:3072) cent, [3072:) new_features

  char* ws = (char*)d_ws;
  u64* maskbuf            = (u64*)(ws + 0);                      // 13,107,200
  unsigned short* featsBF = (unsigned short*)(ws + 13107200);    // 12,800,000
  f32x4* coords4          = (f32x4*)(ws + 25907200);             //  1,600,000
  unsigned short* W1T = (unsigned short*)(ws + 27507200);        //     13,312
  unsigned short* W2T = (unsigned short*)(ws + 27520512);        //      9,216
  unsigned short* W3T = (unsigned short*)(ws + 27529728);        //     18,432

  // prep tail items: 800000 + 100000 + 6656 + 4608 + 9216 + 1024 = 921504
  build_prep_kernel<<<MB_BLKS + 3600, 256, 0, stream>>>(
      coords, features, cidx, W1, b1, W2, W3,
      maskbuf, featsBF, coords4, W1T, W2T, W3T, out);
  fused_kernel<<<KCENT, 512, 0, stream>>>(
      maskbuf, featsBF, coords4, out, b2, b3,
      W1T, W2T, W3T, out + 3072);
}

// Round 11
// 253.050 us; speedup vs baseline: 1.8029x; 1.8029x over previous
//
#include <hip/hip_runtime.h>
#include <hip/hip_bf16.h>

#define NPTS    100000
#define KCENT   1024
#define NSEG    391          // ceil(NPTS/256)
#define NWORDS  1564         // NSEG*4 words of 64 points
#define WSTRIDE 1600         // mask words per centroid (padded)
#define MB_BLKS (NSEG*32)    // 12512 maskbuild blocks
#define UG_BLKS 1563         // ceil(NPTS/64) u-GEMM blocks

typedef __attribute__((ext_vector_type(8))) short bf16x8;   // 8 bf16 (4 VGPRs)
typedef __attribute__((ext_vector_type(4))) float f32x4;
typedef unsigned long long u64;

__device__ __forceinline__ unsigned short f2bf(float x) {
  union { float f; unsigned u; } v; v.f = x;
  unsigned r = v.u + 0x7FFFu + ((v.u >> 16) & 1u);   // RNE
  return (unsigned short)(r >> 16);
}
__device__ __forceinline__ unsigned pk2bf(float a, float b) {
  union { __hip_bfloat162 h; unsigned u; } cv;
  cv.h = __float22bfloat162_rn(make_float2(a, b));
  return cv.u;
}
__device__ __forceinline__ float bf2f(unsigned short s) {
  union { float f; unsigned u; } v; v.u = ((unsigned)s) << 16; return v.f;
}
__device__ __forceinline__ bf16x8 pack_bf8(f32x4 a, f32x4 b) {
  union { bf16x8 v; unsigned u[4]; } r;
  r.u[0] = pk2bf(a[0], a[1]); r.u[1] = pk2bf(a[2], a[3]);
  r.u[2] = pk2bf(b[0], b[1]); r.u[3] = pk2bf(b[2], b[3]);
  return r.v;
}

// ---------------------------------------------------------------- maskbuild + u-GEMM + prep (fused, independent parts)
// blocks [0, MB_BLKS): ball mask via ballot, 32 centroids x 256 points/block
//   (R6-proven). maskbuf[centroid*WSTRIDE + word].
// blocks [MB_BLKS, MB_BLKS+UG_BLKS): u-GEMM — u[p] = W1[3:67]^T·f[p] + b1,
//   64 points/block (4 waves x 16), A-frags from fp32 W1 on the fly, output
//   bf16 row-major via LDS transpose (coalesced uint4 stores).
// blocks beyond: flat prep — coords4, W2T/W3T(72), cent gather -> d_out.
__global__ __launch_bounds__(256) void build_prep_kernel(
    const float* __restrict__ coords, const float* __restrict__ features,
    const int* __restrict__ cidx, const float* __restrict__ W1,
    const float* __restrict__ b1, const float* __restrict__ W2,
    const float* __restrict__ W3, u64* __restrict__ maskbuf,
    unsigned short* __restrict__ uBF, f32x4* __restrict__ coords4,
    unsigned short* __restrict__ W2T, unsigned short* __restrict__ W3T,
    float* __restrict__ outCent) {
  const int bid = blockIdx.x;
  const int tid = threadIdx.x;
  if (bid < MB_BLKS) {
    const int grp = bid / NSEG, seg = bid - grp*NSEG;
    __shared__ float sC[96];
    __shared__ float sCC[32];
    if (tid < 96) sC[tid] = coords[cidx[grp*32 + tid/3]*3 + tid%3];
    __syncthreads();
    if (tid < 32) {
      float x = sC[tid*3], y = sC[tid*3+1], z = sC[tid*3+2];
      sCC[tid] = __fadd_rn(__fadd_rn(__fmul_rn(x,x), __fmul_rn(y,y)), __fmul_rn(z,z));
    }
    const int p = seg*256 + tid;
    const bool inr = p < NPTS;
    float px = 0.f, py = 0.f, pz = 0.f;
    if (inr) { px = coords[p*3]; py = coords[p*3+1]; pz = coords[p*3+2]; }
    const float pp = __fadd_rn(__fadd_rn(__fmul_rn(px,px), __fmul_rn(py,py)), __fmul_rn(pz,pz));
    __syncthreads();
    const int lane = tid & 63, wid = tid >> 6;
    u64 myw = 0ull;
    #pragma unroll
    for (int ci = 0; ci < 32; ++ci) {
      float cx = sC[ci*3], cy = sC[ci*3+1], cz = sC[ci*3+2];
      float dt = __fadd_rn(__fadd_rn(__fmul_rn(cx,px), __fmul_rn(cy,py)), __fmul_rn(cz,pz));
      float d2 = __fsub_rn(__fadd_rn(sCC[ci], pp), __fmul_rn(2.0f, dt));
      bool sel = inr && (d2 <= 0.04f);
      u64 m = __ballot(sel);
      if (lane == ci) myw = m;
    }
    if (lane < 32)
      maskbuf[(u64)(grp*32 + lane)*WSTRIDE + seg*4 + wid] = myw;
    return;
  }
  if (bid < MB_BLKS + UG_BLKS) {
    // ---- u-GEMM: 64 points, u = W1f^T·f + b1 (pre-activation, no relu) ----
    const int pbase = (bid - MB_BLKS) * 64;
    __shared__ __align__(16) unsigned short sU[64*72];
    __shared__ float sB1g[64];
    const int w = tid >> 6, lane = tid & 63;
    const int q = lane >> 4, cl = lane & 15;
    if (tid < 64) sB1g[tid] = b1[tid];
    // A-frags from fp32 W1 (row k+3, col o), bf16 on the fly
    bf16x8 wf[2][4];
    #pragma unroll
    for (int ks = 0; ks < 2; ++ks)
      #pragma unroll
      for (int nt = 0; nt < 4; ++nt) {
        union { bf16x8 v; unsigned short s[8]; } t;
        #pragma unroll
        for (int i = 0; i < 8; ++i)
          t.s[i] = f2bf(W1[(3 + ks*32 + q*8 + i)*64 + nt*16 + cl]);
        wf[ks][nt] = t.v;
      }
    // B-frags from fp32 features
    const int p = pbase + w*16 + cl;
    const int ps = (p < NPTS) ? p : 0;
    bf16x8 xb[2];
    #pragma unroll
    for (int ks = 0; ks < 2; ++ks) {
      const float* fp = features + (u64)ps*64 + ks*32 + q*8;
      xb[ks] = pack_bf8(*(const f32x4*)fp, *(const f32x4*)(fp + 4));
    }
    f32x4 acc[4];
    #pragma unroll
    for (int nt = 0; nt < 4; ++nt) acc[nt] = (f32x4){0.f,0.f,0.f,0.f};
    #pragma unroll
    for (int ks = 0; ks < 2; ++ks)
      #pragma unroll
      for (int nt = 0; nt < 4; ++nt)
        acc[nt] = __builtin_amdgcn_mfma_f32_16x16x32_bf16(wf[ks][nt], xb[ks], acc[nt], 0,0,0);
    __syncthreads();   // sB1g visible
    #pragma unroll
    for (int nt = 0; nt < 4; ++nt) {
      const int o = nt*16 + q*4;
      f32x4 bb = *(const f32x4*)(sB1g + o);
      uint2 pk = { pk2bf(acc[nt][0]+bb[0], acc[nt][1]+bb[1]),
                   pk2bf(acc[nt][2]+bb[2], acc[nt][3]+bb[3]) };
      *(uint2*)(sU + (w*16+cl)*72 + o) = pk;
    }
    __syncthreads();
    #pragma unroll
    for (int it = 0; it < 2; ++it) {
      int i = it*256 + tid;                 // 512 uint4s
      int r = i >> 3, c = i & 7;
      if (pbase + r < NPTS)
        ((uint4*)(uBF + (u64)(pbase + r)*64))[c] = *(const uint4*)(sU + r*72 + c*8);
    }
    return;
  }
  int i = (bid - MB_BLKS - UG_BLKS) * 256 + tid;
  if (i < NPTS) {
    coords4[i] = (f32x4){coords[3*i], coords[3*i+1], coords[3*i+2], 0.f};
    return;
  }
  i -= NPTS;
  if (i < 4608) { int n = i / 72, kk = i - n*72;
    W2T[n*72 + kk] = f2bf(kk < 64 ? W2[kk*64 + n] : 0.f); return; }
  i -= 4608;
  if (i < 9216) { int n = i / 72, kk = i - n*72;
    W3T[n*72 + kk] = f2bf(kk < 64 ? W3[kk*128 + n] : 0.f); return; }
  i -= 9216;
  if (i < KCENT) {
    int ci = cidx[i];
    outCent[i*3+0] = coords[ci*3+0];
    outCent[i*3+1] = coords[ci*3+1];
    outCent[i*3+2] = coords[ci*3+2];
  }
}

// ---------------------------------------------------------------- mega-fused: scan + MLP + maxpool + epilogue
// One block per centroid (R6 schedule: 4 waves, dual 16-pt columns A/B,
// 2 waves/SIMD). Phase 1: ordered mask compaction into sIdx. Phase 2:
// L1 = per-lane fp32 epilogue on prefetched u-frags (h1 stays IN REGISTERS,
// B-frag layout — no LDS round-trip, no L1 MFMA); L2 = MFMA, W2 from LDS,
// h2 via LDS; L3 = MFMA in 4-nt halves (W3 frags in regs) + masked maxpool.
// Phase 3: block max-pool, +b3, relu, store.
__global__ __launch_bounds__(256, 2) void fused_kernel(
    const u64* __restrict__ maskbuf, const unsigned short* __restrict__ uBF,
    const f32x4* __restrict__ coords4, const float* __restrict__ cent,
    const float* __restrict__ W1g, const float* __restrict__ b2v,
    const float* __restrict__ b3v, const unsigned short* __restrict__ gW2T,
    const unsigned short* __restrict__ gW3T, float* __restrict__ outF) {
  __shared__ __align__(16) unsigned short sW2T[64*72];
  __shared__ __align__(16) unsigned short sH[4*2*16*72];  // per-wave A/B h2-bufs
  __shared__ int sIdx[KCENT];
  __shared__ int sTot[4];
  __shared__ float sW1a[192];
  __shared__ float sB2[64], sB3[128];
  __shared__ float sMax[512];

  const int k = blockIdx.x;
  const int tid = threadIdx.x;
  const int w = tid >> 6, lane = tid & 63;
  const int q = lane >> 4, cl = lane & 15;

  // mask preloads issue first (cover scan rounds 0..2)
  const u64* M = maskbuf + (u64)k * WSTRIDE;
  u64 wv0 = M[tid], wv1 = M[256 + tid], wv2 = M[512 + tid];

  for (int i = tid; i < 576; i += 256) ((uint4*)sW2T)[i] = ((const uint4*)gW2T)[i];
  if (tid < 192) sW1a[tid] = W1g[tid];     // W1 rows 0..2 (rel part), fp32
  if (tid < 64)  sB2[tid] = b2v[tid];
  if (tid < 128) sB3[tid] = b3v[tid];

  // W3 fragments in regs
  bf16x8 w3f[2][8];
  #pragma unroll
  for (int ks = 0; ks < 2; ++ks)
    #pragma unroll
    for (int nt = 0; nt < 8; ++nt)
      w3f[ks][nt] = *(const bf16x8*)(gW3T + (nt*16+cl)*72 + ks*32 + q*8);

  const float cx = cent[k*3], cy = cent[k*3+1], cz = cent[k*3+2];

  // ---- phase 1: ordered compaction into sIdx ----
  int base = 0;
  #pragma unroll 1
  for (int r = 0; r < 7; ++r) {
    const int widx = r*256 + tid;
    u64 word = (r == 0) ? wv0 : (r == 1) ? wv1 : (r == 2) ? wv2
             : ((widx < NWORDS) ? M[widx] : 0ull);
    int pc = __popcll(word);
    int inc = pc;                      // wave-inclusive scan
    #pragma unroll
    for (int d = 1; d < 64; d <<= 1) {
      int t = __shfl_up(inc, d);
      if (lane >= d) inc += t;
    }
    if (lane == 63) sTot[w] = inc;
    __syncthreads();
    int wbase = 0, tot = 0;
    #pragma unroll
    for (int i = 0; i < 4; ++i) { int v = sTot[i]; tot += v; if (i < w) wbase += v; }
    int pos = base + wbase + inc - pc;
    const int pbase = widx * 64;
    while (word != 0ull && pos < KCENT) {
      int b = __ffsll(word) - 1;
      sIdx[pos++] = pbase + b;
      word &= word - 1ull;
    }
    base += tot;
    __syncthreads();                   // sIdx visible (also covers sW1a/sB2/sB3/sW2T staging)
    if (base >= KCENT) break;          // uniform
  }
  const int count = base < KCENT ? base : KCENT;   // uniform across block

  // hoist per-lane W1-rel constants: channels set0 = q*8..+8, set1 = 32+q*8..+8
  float a00[8], a01[8], a10[8], a11[8], a20[8], a21[8];
  #pragma unroll
  for (int i = 0; i < 8; ++i) {
    const int c0 = q*8 + i, c1 = 32 + q*8 + i;
    a00[i] = sW1a[c0];       a01[i] = sW1a[c1];
    a10[i] = sW1a[64 + c0];  a11[i] = sW1a[64 + c1];
    a20[i] = sW1a[128 + c0]; a21[i] = sW1a[128 + c1];
  }

  unsigned short* myHA = sH + w*2304;
  unsigned short* myHB = myHA + 1152;

  f32x4 runmax[8];
  #pragma unroll
  for (int i = 0; i < 8; ++i)
    runmax[i] = (f32x4){-__builtin_inff(), -__builtin_inff(),
                        -__builtin_inff(), -__builtin_inff()};

  // ---- phase 2: MLP over pairs of 16-point columns ----
  const int nstrips = (count + 15) >> 4;
  const int npairs  = (nstrips + 1) >> 1;
  int pp = w;

  int pA = 0, pB = 0;
  { int jA = 32*pp + cl;      if (jA < count) pA = sIdx[jA];
    int jB = 32*pp + 16 + cl; if (jB < count) pB = sIdx[jB]; }
  f32x4  c4A = coords4[pA], c4B = coords4[pB];
  bf16x8 xfA0 = *(const bf16x8*)(uBF + pA*64 + q*8);
  bf16x8 xfA1 = *(const bf16x8*)(uBF + pA*64 + 32 + q*8);
  bf16x8 xfB0 = *(const bf16x8*)(uBF + pB*64 + q*8);
  bf16x8 xfB1 = *(const bf16x8*)(uBF + pB*64 + 32 + q*8);
  int pA2 = 0, pB2 = 0;
  { int jA = 32*(pp+4) + cl;      if (jA < count) pA2 = sIdx[jA];
    int jB = 32*(pp+4) + 16 + cl; if (jB < count) pB2 = sIdx[jB]; }

  for (; pp < npairs; pp += 4) {
    // idx (LDS) two iterations ahead
    int pA3 = 0, pB3 = 0;
    { int jA = 32*(pp+8) + cl;      if (jA < count) pA3 = sIdx[jA];
      int jB = 32*(pp+8) + 16 + cl; if (jB < count) pB3 = sIdx[jB]; }

    // ---- layer 1: fp32 epilogue on u-frags, h1 stays in registers ----
    bf16x8 hbA0, hbA1, hbB0, hbB1;
    {
      const float rxA = c4A[0]-cx, ryA = c4A[1]-cy, rzA = c4A[2]-cz;
      const float rxB = c4B[0]-cx, ryB = c4B[1]-cy, rzB = c4B[2]-cz;
      union { bf16x8 v; unsigned short s[8]; } uA0, uA1, uB0, uB1;
      uA0.v = xfA0; uA1.v = xfA1; uB0.v = xfB0; uB1.v = xfB1;
      union { bf16x8 v; unsigned u[4]; } oA0, oA1, oB0, oB1;
      #pragma unroll
      for (int i = 0; i < 8; i += 2) {
        float vA0a = bf2f(uA0.s[i])   + rxA*a00[i]   + ryA*a10[i]   + rzA*a20[i];
        float vA0b = bf2f(uA0.s[i+1]) + rxA*a00[i+1] + ryA*a10[i+1] + rzA*a20[i+1];
        oA0.u[i>>1] = pk2bf(fmaxf(vA0a, 0.f), fmaxf(vA0b, 0.f));
        float vA1a = bf2f(uA1.s[i])   + rxA*a01[i]   + ryA*a11[i]   + rzA*a21[i];
        float vA1b = bf2f(uA1.s[i+1]) + rxA*a01[i+1] + ryA*a11[i+1] + rzA*a21[i+1];
        oA1.u[i>>1] = pk2bf(fmaxf(vA1a, 0.f), fmaxf(vA1b, 0.f));
        float vB0a = bf2f(uB0.s[i])   + rxB*a00[i]   + ryB*a10[i]   + rzB*a20[i];
        float vB0b = bf2f(uB0.s[i+1]) + rxB*a00[i+1] + ryB*a10[i+1] + rzB*a20[i+1];
        oB0.u[i>>1] = pk2bf(fmaxf(vB0a, 0.f), fmaxf(vB0b, 0.f));
        float vB1a = bf2f(uB1.s[i])   + rxB*a01[i]   + ryB*a11[i]   + rzB*a21[i];
        float vB1b = bf2f(uB1.s[i+1]) + rxB*a01[i+1] + ryB*a11[i+1] + rzB*a21[i+1];
        oB1.u[i>>1] = pk2bf(fmaxf(vB1a, 0.f), fmaxf(vB1b, 0.f));
      }
      hbA0 = oA0.v; hbA1 = oA1.v; hbB0 = oB0.v; hbB1 = oB1.v;
    }

    // current u/c4 dead: issue next pair's data loads (hide under L2+L3)
    c4A = coords4[pA2]; c4B = coords4[pB2];
    xfA0 = *(const bf16x8*)(uBF + pA2*64 + q*8);
    xfA1 = *(const bf16x8*)(uBF + pA2*64 + 32 + q*8);
    xfB0 = *(const bf16x8*)(uBF + pB2*64 + q*8);
    xfB1 = *(const bf16x8*)(uBF + pB2*64 + 32 + q*8);

    // ---- layer 2 (W2 frags from LDS, h1 from regs) -> h2 to LDS ----
    {
      f32x4 accA[4], accB[4];
      #pragma unroll
      for (int nt = 0; nt < 4; ++nt) { accA[nt] = (f32x4){0.f,0.f,0.f,0.f};
                                       accB[nt] = (f32x4){0.f,0.f,0.f,0.f}; }
      #pragma unroll
      for (int nt = 0; nt < 4; ++nt) {
        const unsigned short* wrow = sW2T + (nt*16+cl)*72 + q*8;
        bf16x8 wa0 = *(const bf16x8*)(wrow);
        accA[nt] = __builtin_amdgcn_mfma_f32_16x16x32_bf16(wa0, hbA0, accA[nt], 0,0,0);
        accB[nt] = __builtin_amdgcn_mfma_f32_16x16x32_bf16(wa0, hbB0, accB[nt], 0,0,0);
        bf16x8 wa1 = *(const bf16x8*)(wrow + 32);
        accA[nt] = __builtin_amdgcn_mfma_f32_16x16x32_bf16(wa1, hbA1, accA[nt], 0,0,0);
        accB[nt] = __builtin_amdgcn_mfma_f32_16x16x32_bf16(wa1, hbB1, accB[nt], 0,0,0);
      }
      #pragma unroll
      for (int nt = 0; nt < 4; ++nt) {
        const int o = nt*16 + q*4;
        f32x4 bb = *(const f32x4*)(sB2 + o);
        uint2 pkA = { pk2bf(fmaxf(accA[nt][0]+bb[0],0.f), fmaxf(accA[nt][1]+bb[1],0.f)),
                      pk2bf(fmaxf(accA[nt][2]+bb[2],0.f), fmaxf(accA[nt][3]+bb[3],0.f)) };
        *(uint2*)(myHA + cl*72 + o) = pkA;
        uint2 pkB = { pk2bf(fmaxf(accB[nt][0]+bb[0],0.f), fmaxf(accB[nt][1]+bb[1],0.f)),
                      pk2bf(fmaxf(accB[nt][2]+bb[2],0.f), fmaxf(accB[nt][3]+bb[3],0.f)) };
        *(uint2*)(myHB + cl*72 + o) = pkB;
      }
    }

    // ---- layer 3 in 4-nt halves (W3 frags in regs) + masked maxpool ----
    {
      bf16x8 hA0 = *(const bf16x8*)(myHA + cl*72 + q*8);
      bf16x8 hA1 = *(const bf16x8*)(myHA + cl*72 + 32 + q*8);
      bf16x8 hB0 = *(const bf16x8*)(myHB + cl*72 + q*8);
      bf16x8 hB1 = *(const bf16x8*)(myHB + cl*72 + 32 + q*8);
      const float vmA = (32*pp + cl      < count) ? 0.f : -__builtin_inff();
      const float vmB = (32*pp + 16 + cl < count) ? 0.f : -__builtin_inff();
      #pragma unroll
      for (int half = 0; half < 2; ++half) {
        f32x4 a3A[4], a3B[4];
        #pragma unroll
        for (int j = 0; j < 4; ++j) { a3A[j] = (f32x4){0.f,0.f,0.f,0.f};
                                      a3B[j] = (f32x4){0.f,0.f,0.f,0.f}; }
        #pragma unroll
        for (int j = 0; j < 4; ++j) {
          const int nt = half*4 + j;
          a3A[j] = __builtin_amdgcn_mfma_f32_16x16x32_bf16(w3f[0][nt], hA0, a3A[j], 0,0,0);
          a3B[j] = __builtin_amdgcn_mfma_f32_16x16x32_bf16(w3f[0][nt], hB0, a3B[j], 0,0,0);
        }
        #pragma unroll
        for (int j = 0; j < 4; ++j) {
          const int nt = half*4 + j;
          a3A[j] = __builtin_amdgcn_mfma_f32_16x16x32_bf16(w3f[1][nt], hA1, a3A[j], 0,0,0);
          a3B[j] = __builtin_amdgcn_mfma_f32_16x16x32_bf16(w3f[1][nt], hB1, a3B[j], 0,0,0);
        }
        #pragma unroll
        for (int j = 0; j < 4; ++j) {
          const int nt = half*4 + j;
          #pragma unroll
          for (int r = 0; r < 4; ++r)
            runmax[nt][r] = fmaxf(runmax[nt][r],
                                  fmaxf(a3A[j][r] + vmA, a3B[j][r] + vmB));
        }
      }
    }

    pA2 = pA3; pB2 = pB3;
  }

  // ---- phase 3: reduce over points, +b3, relu, store ----
  #pragma unroll
  for (int nt = 0; nt < 8; ++nt) {
    #pragma unroll
    for (int r = 0; r < 4; ++r) {
      float m = runmax[nt][r];
      m = fmaxf(m, __shfl_xor(m, 1));
      m = fmaxf(m, __shfl_xor(m, 2));
      m = fmaxf(m, __shfl_xor(m, 4));
      m = fmaxf(m, __shfl_xor(m, 8));
      runmax[nt][r] = m;
    }
    if (cl == 0) *(f32x4*)(sMax + w*128 + nt*16 + q*4) = runmax[nt];
  }
  __syncthreads();
  if (tid < 128) {
    float m = fmaxf(fmaxf(sMax[tid], sMax[128+tid]),
                    fmaxf(sMax[256+tid], sMax[384+tid]));
    outF[k*128 + tid] = fmaxf(m + sB3[tid], 0.f);
  }
}

// ---------------------------------------------------------------- launch
extern "C" void kernel_launch(void* const* d_in, const int* in_sizes, int n_in,
                              void* d_out, int out_size, void* d_ws, size_t ws_size,
                              hipStream_t stream) {
  const float* coords   = (const float*)d_in[0];
  const float* features = (const float*)d_in[1];
  const int*   cidx     = (const int*)d_in[2];
  const float* W1 = (const float*)d_in[3];
  const float* b1 = (const float*)d_in[4];
  const float* W2 = (const float*)d_in[5];
  const float* b2 = (const float*)d_in[6];
  const float* W3 = (const float*)d_in[7];
  const float* b3 = (const float*)d_in[8];
  float* out = (float*)d_out;           // [0:3072) cent, [3072:) new_features

  char* ws = (char*)d_ws;
  u64* maskbuf        = (u64*)(ws + 0);                      // 13,107,200
  unsigned short* uBF = (unsigned short*)(ws + 13107200);    // 12,800,000
  f32x4* coords4      = (f32x4*)(ws + 25907200);             //  1,600,000
  unsigned short* W2T = (unsigned short*)(ws + 27507200);    //      9,216
  unsigned short* W3T = (unsigned short*)(ws + 27516416);    //     18,432

  // flat tail items: 100000 + 4608 + 9216 + 1024 = 114848 -> 449 blocks
  build_prep_kernel<<<MB_BLKS + UG_BLKS + 449, 256, 0, stream>>>(
      coords, features, cidx, W1, b1, W2, W3,
      maskbuf, uBF, coords4, W2T, W3T, out);
  fused_kernel<<<KCENT, 256, 0, stream>>>(
      maskbuf, uBF, coords4, out, W1, b2, b3,
      W2T, W3T, out + 3072);
}

// Round 12
// 249.008 us; speedup vs baseline: 1.8321x; 1.0162x over previous
//
#include <hip/hip_runtime.h>
#include <hip/hip_bf16.h>

#define NPTS    100000
#define KCENT   1024
#define NSEG    391          // ceil(NPTS/256)
#define NWORDS  1564         // NSEG*4 words of 64 points
#define WSTRIDE 1600         // mask words per centroid (padded)
#define MB_BLKS (NSEG*32)    // 12512 maskbuild blocks
#define UG_BLKS 1563         // ceil(NPTS/64) u-GEMM blocks

typedef __attribute__((ext_vector_type(8))) short bf16x8;   // 8 bf16 (4 VGPRs)
typedef __attribute__((ext_vector_type(4))) float f32x4;
typedef unsigned long long u64;

__device__ __forceinline__ unsigned short f2bf(float x) {
  union { float f; unsigned u; } v; v.f = x;
  unsigned r = v.u + 0x7FFFu + ((v.u >> 16) & 1u);   // RNE
  return (unsigned short)(r >> 16);
}
__device__ __forceinline__ unsigned pk2bf(float a, float b) {
  union { __hip_bfloat162 h; unsigned u; } cv;
  cv.h = __float22bfloat162_rn(make_float2(a, b));
  return cv.u;
}
__device__ __forceinline__ float bf2f(unsigned short s) {
  union { float f; unsigned u; } v; v.u = ((unsigned)s) << 16; return v.f;
}
__device__ __forceinline__ bf16x8 pack_bf8(f32x4 a, f32x4 b) {
  union { bf16x8 v; unsigned u[4]; } r;
  r.u[0] = pk2bf(a[0], a[1]); r.u[1] = pk2bf(a[2], a[3]);
  r.u[2] = pk2bf(b[0], b[1]); r.u[3] = pk2bf(b[2], b[3]);
  return r.v;
}

// ---------------------------------------------------------------- maskbuild + u-GEMM + prep (fused, independent parts)
// blocks [0, MB_BLKS): ball mask via ballot, 32 centroids x 256 points/block.
//   Centroid (x,y,z,cc) packed as one f32x4 in LDS -> 1 ds_read_b128/iter.
//   maskbuf[centroid*WSTRIDE + word] (centroid-major, R6-proven for fused).
// blocks [MB_BLKS, MB_BLKS+UG_BLKS): u-GEMM — u[p] = W1[3:67]^T·f[p] + b1,
//   64 points/block, bf16 row-major out via LDS transpose.
// blocks beyond: flat prep — coords4, W2T/W3T(72), cent gather -> d_out.
__global__ __launch_bounds__(256) void build_prep_kernel(
    const float* __restrict__ coords, const float* __restrict__ features,
    const int* __restrict__ cidx, const float* __restrict__ W1,
    const float* __restrict__ b1, const float* __restrict__ W2,
    const float* __restrict__ W3, u64* __restrict__ maskbuf,
    unsigned short* __restrict__ uBF, f32x4* __restrict__ coords4,
    unsigned short* __restrict__ W2T, unsigned short* __restrict__ W3T,
    float* __restrict__ outCent) {
  const int bid = blockIdx.x;
  const int tid = threadIdx.x;
  if (bid < MB_BLKS) {
    const int grp = bid / NSEG, seg = bid - grp*NSEG;
    __shared__ __align__(16) f32x4 sC4[32];    // (cx, cy, cz, cc)
    if (tid < 32) {
      int c = cidx[grp*32 + tid];
      float x = coords[c*3], y = coords[c*3+1], z = coords[c*3+2];
      float cc = __fadd_rn(__fadd_rn(__fmul_rn(x,x), __fmul_rn(y,y)), __fmul_rn(z,z));
      sC4[tid] = (f32x4){x, y, z, cc};
    }
    const int p = seg*256 + tid;
    const bool inr = p < NPTS;
    float px = 0.f, py = 0.f, pz = 0.f;
    if (inr) { px = coords[p*3]; py = coords[p*3+1]; pz = coords[p*3+2]; }
    const float pp = __fadd_rn(__fadd_rn(__fmul_rn(px,px), __fmul_rn(py,py)), __fmul_rn(pz,pz));
    __syncthreads();
    const int lane = tid & 63, wid = tid >> 6;
    u64 myw = 0ull;
    #pragma unroll
    for (int ci = 0; ci < 32; ++ci) {
      f32x4 C = sC4[ci];
      float dt = __fadd_rn(__fadd_rn(__fmul_rn(C[0],px), __fmul_rn(C[1],py)), __fmul_rn(C[2],pz));
      float d2 = __fsub_rn(__fadd_rn(C[3], pp), __fmul_rn(2.0f, dt));
      bool sel = inr && (d2 <= 0.04f);
      u64 m = __ballot(sel);
      if (lane == ci) myw = m;
    }
    if (lane < 32)
      maskbuf[(u64)(grp*32 + lane)*WSTRIDE + seg*4 + wid] = myw;
    return;
  }
  if (bid < MB_BLKS + UG_BLKS) {
    // ---- u-GEMM: 64 points, u = W1f^T·f + b1 (pre-activation, no relu) ----
    const int pbase = (bid - MB_BLKS) * 64;
    __shared__ __align__(16) unsigned short sU[64*72];
    __shared__ float sB1g[64];
    const int w = tid >> 6, lane = tid & 63;
    const int q = lane >> 4, cl = lane & 15;
    if (tid < 64) sB1g[tid] = b1[tid];
    bf16x8 wf[2][4];
    #pragma unroll
    for (int ks = 0; ks < 2; ++ks)
      #pragma unroll
      for (int nt = 0; nt < 4; ++nt) {
        union { bf16x8 v; unsigned short s[8]; } t;
        #pragma unroll
        for (int i = 0; i < 8; ++i)
          t.s[i] = f2bf(W1[(3 + ks*32 + q*8 + i)*64 + nt*16 + cl]);
        wf[ks][nt] = t.v;
      }
    const int p = pbase + w*16 + cl;
    const int ps = (p < NPTS) ? p : 0;
    bf16x8 xb[2];
    #pragma unroll
    for (int ks = 0; ks < 2; ++ks) {
      const float* fp = features + (u64)ps*64 + ks*32 + q*8;
      xb[ks] = pack_bf8(*(const f32x4*)fp, *(const f32x4*)(fp + 4));
    }
    f32x4 acc[4];
    #pragma unroll
    for (int nt = 0; nt < 4; ++nt) acc[nt] = (f32x4){0.f,0.f,0.f,0.f};
    #pragma unroll
    for (int ks = 0; ks < 2; ++ks)
      #pragma unroll
      for (int nt = 0; nt < 4; ++nt)
        acc[nt] = __builtin_amdgcn_mfma_f32_16x16x32_bf16(wf[ks][nt], xb[ks], acc[nt], 0,0,0);
    __syncthreads();   // sB1g visible
    #pragma unroll
    for (int nt = 0; nt < 4; ++nt) {
      const int o = nt*16 + q*4;
      f32x4 bb = *(const f32x4*)(sB1g + o);
      uint2 pk = { pk2bf(acc[nt][0]+bb[0], acc[nt][1]+bb[1]),
                   pk2bf(acc[nt][2]+bb[2], acc[nt][3]+bb[3]) };
      *(uint2*)(sU + (w*16+cl)*72 + o) = pk;
    }
    __syncthreads();
    #pragma unroll
    for (int it = 0; it < 2; ++it) {
      int i = it*256 + tid;                 // 512 uint4s
      int r = i >> 3, c = i & 7;
      if (pbase + r < NPTS)
        ((uint4*)(uBF + (u64)(pbase + r)*64))[c] = *(const uint4*)(sU + r*72 + c*8);
    }
    return;
  }
  int i = (bid - MB_BLKS - UG_BLKS) * 256 + tid;
  if (i < NPTS) {
    coords4[i] = (f32x4){coords[3*i], coords[3*i+1], coords[3*i+2], 0.f};
    return;
  }
  i -= NPTS;
  if (i < 4608) { int n = i / 72, kk = i - n*72;
    W2T[n*72 + kk] = f2bf(kk < 64 ? W2[kk*64 + n] : 0.f); return; }
  i -= 4608;
  if (i < 9216) { int n = i / 72, kk = i - n*72;
    W3T[n*72 + kk] = f2bf(kk < 64 ? W3[kk*128 + n] : 0.f); return; }
  i -= 9216;
  if (i < KCENT) {
    int ci = cidx[i];
    outCent[i*3+0] = coords[ci*3+0];
    outCent[i*3+1] = coords[ci*3+1];
    outCent[i*3+2] = coords[ci*3+2];
  }
}

// ---------------------------------------------------------------- mega-fused: scan + MLP + maxpool + epilogue
// One block per centroid (R6 schedule: 4 waves, dual 16-pt columns A/B,
// 2 waves/SIMD). L1 = per-lane fp32 epilogue on prefetched u-frags, with
// W1-rel coefficients read from LDS per iteration IN TWO HALVES (24 transient
// regs, not 48 resident — the R11 spill fix). h1 stays in registers. L2 =
// MFMA (W2 from LDS) -> h2 via LDS; L3 = MFMA in 4-nt halves (W3 frags in
// regs/AGPRs) + masked maxpool. Phase 3: block max-pool, +b3, relu, store.
__global__ __launch_bounds__(256, 2) void fused_kernel(
    const u64* __restrict__ maskbuf, const unsigned short* __restrict__ uBF,
    const f32x4* __restrict__ coords4, const float* __restrict__ cent,
    const float* __restrict__ W1g, const float* __restrict__ b2v,
    const float* __restrict__ b3v, const unsigned short* __restrict__ gW2T,
    const unsigned short* __restrict__ gW3T, float* __restrict__ outF) {
  __shared__ __align__(16) unsigned short sW2T[64*72];
  __shared__ __align__(16) unsigned short sH[4*2*16*72];  // per-wave A/B h2-bufs
  __shared__ int sIdx[KCENT];
  __shared__ int sTot[4];
  __shared__ __align__(16) float sW1a[192];
  __shared__ float sB2[64], sB3[128];
  __shared__ float sMax[512];

  const int k = blockIdx.x;
  const int tid = threadIdx.x;
  const int w = tid >> 6, lane = tid & 63;
  const int q = lane >> 4, cl = lane & 15;

  // mask preloads issue first (cover scan rounds 0..2)
  const u64* M = maskbuf + (u64)k * WSTRIDE;
  u64 wv0 = M[tid], wv1 = M[256 + tid], wv2 = M[512 + tid];

  for (int i = tid; i < 576; i += 256) ((uint4*)sW2T)[i] = ((const uint4*)gW2T)[i];
  if (tid < 192) sW1a[tid] = W1g[tid];     // W1 rows 0..2 (rel part), fp32
  if (tid < 64)  sB2[tid] = b2v[tid];
  if (tid < 128) sB3[tid] = b3v[tid];

  // W3 fragments in regs (AGPR-eligible: only feed MFMA A-operand)
  bf16x8 w3f[2][8];
  #pragma unroll
  for (int ks = 0; ks < 2; ++ks)
    #pragma unroll
    for (int nt = 0; nt < 8; ++nt)
      w3f[ks][nt] = *(const bf16x8*)(gW3T + (nt*16+cl)*72 + ks*32 + q*8);

  const float cx = cent[k*3], cy = cent[k*3+1], cz = cent[k*3+2];

  // ---- phase 1: ordered compaction into sIdx ----
  int base = 0;
  #pragma unroll 1
  for (int r = 0; r < 7; ++r) {
    const int widx = r*256 + tid;
    u64 word = (r == 0) ? wv0 : (r == 1) ? wv1 : (r == 2) ? wv2
             : ((widx < NWORDS) ? M[widx] : 0ull);
    int pc = __popcll(word);
    int inc = pc;                      // wave-inclusive scan
    #pragma unroll
    for (int d = 1; d < 64; d <<= 1) {
      int t = __shfl_up(inc, d);
      if (lane >= d) inc += t;
    }
    if (lane == 63) sTot[w] = inc;
    __syncthreads();
    int wbase = 0, tot = 0;
    #pragma unroll
    for (int i = 0; i < 4; ++i) { int v = sTot[i]; tot += v; if (i < w) wbase += v; }
    int pos = base + wbase + inc - pc;
    const int pbase = widx * 64;
    while (word != 0ull && pos < KCENT) {
      int b = __ffsll(word) - 1;
      sIdx[pos++] = pbase + b;
      word &= word - 1ull;
    }
    base += tot;
    __syncthreads();                   // sIdx visible (also covers LDS staging)
    if (base >= KCENT) break;          // uniform
  }
  const int count = base < KCENT ? base : KCENT;   // uniform across block

  unsigned short* myHA = sH + w*2304;
  unsigned short* myHB = myHA + 1152;

  f32x4 runmax[8];
  #pragma unroll
  for (int i = 0; i < 8; ++i)
    runmax[i] = (f32x4){-__builtin_inff(), -__builtin_inff(),
                        -__builtin_inff(), -__builtin_inff()};

  // ---- phase 2: MLP over pairs of 16-point columns ----
  const int nstrips = (count + 15) >> 4;
  const int npairs  = (nstrips + 1) >> 1;
  int pp = w;

  int pA = 0, pB = 0;
  { int jA = 32*pp + cl;      if (jA < count) pA = sIdx[jA];
    int jB = 32*pp + 16 + cl; if (jB < count) pB = sIdx[jB]; }
  f32x4  c4A = coords4[pA], c4B = coords4[pB];
  bf16x8 xfA0 = *(const bf16x8*)(uBF + pA*64 + q*8);
  bf16x8 xfA1 = *(const bf16x8*)(uBF + pA*64 + 32 + q*8);
  bf16x8 xfB0 = *(const bf16x8*)(uBF + pB*64 + q*8);
  bf16x8 xfB1 = *(const bf16x8*)(uBF + pB*64 + 32 + q*8);
  int pA2 = 0, pB2 = 0;
  { int jA = 32*(pp+4) + cl;      if (jA < count) pA2 = sIdx[jA];
    int jB = 32*(pp+4) + 16 + cl; if (jB < count) pB2 = sIdx[jB]; }

  for (; pp < npairs; pp += 4) {
    // idx (LDS) two iterations ahead
    int pA3 = 0, pB3 = 0;
    { int jA = 32*(pp+8) + cl;      if (jA < count) pA3 = sIdx[jA];
      int jB = 32*(pp+8) + 16 + cl; if (jB < count) pB3 = sIdx[jB]; }

    // ---- layer 1: fp32 epilogue on u-frags; W1-rel coeffs from LDS in
    //      two sequential halves (spill fix). h1 stays in registers. ----
    const float rxA = c4A[0]-cx, ryA = c4A[1]-cy, rzA = c4A[2]-cz;
    const float rxB = c4B[0]-cx, ryB = c4B[1]-cy, rzB = c4B[2]-cz;
    bf16x8 hbA0, hbA1, hbB0, hbB1;
    #pragma unroll
    for (int st = 0; st < 2; ++st) {
      // coeffs for channels st*32 + q*8 .. +8, rows 0..2 (broadcast reads)
      f32x4 c0l = *(const f32x4*)(sW1a +        st*32 + q*8);
      f32x4 c0h = *(const f32x4*)(sW1a +        st*32 + q*8 + 4);
      f32x4 c1l = *(const f32x4*)(sW1a +  64 +  st*32 + q*8);
      f32x4 c1h = *(const f32x4*)(sW1a +  64 +  st*32 + q*8 + 4);
      f32x4 c2l = *(const f32x4*)(sW1a + 128 +  st*32 + q*8);
      f32x4 c2h = *(const f32x4*)(sW1a + 128 +  st*32 + q*8 + 4);
      union { bf16x8 v; unsigned short s[8]; } uA, uB;
      uA.v = st ? xfA1 : xfA0;
      uB.v = st ? xfB1 : xfB0;
      union { bf16x8 v; unsigned u[4]; } oA, oB;
      #pragma unroll
      for (int i = 0; i < 8; i += 2) {
        float w0a = (i < 4) ? c0l[i]   : c0h[i-4];
        float w0b = (i < 4) ? c0l[i+1] : c0h[i-3];
        float w1a = (i < 4) ? c1l[i]   : c1h[i-4];
        float w1b = (i < 4) ? c1l[i+1] : c1h[i-3];
        float w2a = (i < 4) ? c2l[i]   : c2h[i-4];
        float w2b = (i < 4) ? c2l[i+1] : c2h[i-3];
        float vAa = bf2f(uA.s[i])   + rxA*w0a + ryA*w1a + rzA*w2a;
        float vAb = bf2f(uA.s[i+1]) + rxA*w0b + ryA*w1b + rzA*w2b;
        oA.u[i>>1] = pk2bf(fmaxf(vAa, 0.f), fmaxf(vAb, 0.f));
        float vBa = bf2f(uB.s[i])   + rxB*w0a + ryB*w1a + rzB*w2a;
        float vBb = bf2f(uB.s[i+1]) + rxB*w0b + ryB*w1b + rzB*w2b;
        oB.u[i>>1] = pk2bf(fmaxf(vBa, 0.f), fmaxf(vBb, 0.f));
      }
      if (st == 0) { hbA0 = oA.v; hbB0 = oB.v; }
      else         { hbA1 = oA.v; hbB1 = oB.v; }
    }

    // current u/c4 dead: issue next pair's data loads (hide under L2+L3)
    c4A = coords4[pA2]; c4B = coords4[pB2];
    xfA0 = *(const bf16x8*)(uBF + pA2*64 + q*8);
    xfA1 = *(const bf16x8*)(uBF + pA2*64 + 32 + q*8);
    xfB0 = *(const bf16x8*)(uBF + pB2*64 + q*8);
    xfB1 = *(const bf16x8*)(uBF + pB2*64 + 32 + q*8);

    // ---- layer 2 (W2 frags from LDS, h1 from regs) -> h2 to LDS ----
    {
      f32x4 accA[4], accB[4];
      #pragma unroll
      for (int nt = 0; nt < 4; ++nt) { accA[nt] = (f32x4){0.f,0.f,0.f,0.f};
                                       accB[nt] = (f32x4){0.f,0.f,0.f,0.f}; }
      #pragma unroll
      for (int nt = 0; nt < 4; ++nt) {
        const unsigned short* wrow = sW2T + (nt*16+cl)*72 + q*8;
        bf16x8 wa0 = *(const bf16x8*)(wrow);
        accA[nt] = __builtin_amdgcn_mfma_f32_16x16x32_bf16(wa0, hbA0, accA[nt], 0,0,0);
        accB[nt] = __builtin_amdgcn_mfma_f32_16x16x32_bf16(wa0, hbB0, accB[nt], 0,0,0);
        bf16x8 wa1 = *(const bf16x8*)(wrow + 32);
        accA[nt] = __builtin_amdgcn_mfma_f32_16x16x32_bf16(wa1, hbA1, accA[nt], 0,0,0);
        accB[nt] = __builtin_amdgcn_mfma_f32_16x16x32_bf16(wa1, hbB1, accB[nt], 0,0,0);
      }
      #pragma unroll
      for (int nt = 0; nt < 4; ++nt) {
        const int o = nt*16 + q*4;
        f32x4 bb = *(const f32x4*)(sB2 + o);
        uint2 pkA = { pk2bf(fmaxf(accA[nt][0]+bb[0],0.f), fmaxf(accA[nt][1]+bb[1],0.f)),
                      pk2bf(fmaxf(accA[nt][2]+bb[2],0.f), fmaxf(accA[nt][3]+bb[3],0.f)) };
        *(uint2*)(myHA + cl*72 + o) = pkA;
        uint2 pkB = { pk2bf(fmaxf(accB[nt][0]+bb[0],0.f), fmaxf(accB[nt][1]+bb[1],0.f)),
                      pk2bf(fmaxf(accB[nt][2]+bb[2],0.f), fmaxf(accB[nt][3]+bb[3],0.f)) };
        *(uint2*)(myHB + cl*72 + o) = pkB;
      }
    }

    // ---- layer 3 in 4-nt halves (W3 frags in regs) + masked maxpool ----
    {
      bf16x8 hA0 = *(const bf16x8*)(myHA + cl*72 + q*8);
      bf16x8 hA1 = *(const bf16x8*)(myHA + cl*72 + 32 + q*8);
      bf16x8 hB0 = *(const bf16x8*)(myHB + cl*72 + q*8);
      bf16x8 hB1 = *(const bf16x8*)(myHB + cl*72 + 32 + q*8);
      const float vmA = (32*pp + cl      < count) ? 0.f : -__builtin_inff();
      const float vmB = (32*pp + 16 + cl < count) ? 0.f : -__builtin_inff();
      #pragma unroll
      for (int half = 0; half < 2; ++half) {
        f32x4 a3A[4], a3B[4];
        #pragma unroll
        for (int j = 0; j < 4; ++j) { a3A[j] = (f32x4){0.f,0.f,0.f,0.f};
                                      a3B[j] = (f32x4){0.f,0.f,0.f,0.f}; }
        #pragma unroll
        for (int j = 0; j < 4; ++j) {
          const int nt = half*4 + j;
          a3A[j] = __builtin_amdgcn_mfma_f32_16x16x32_bf16(w3f[0][nt], hA0, a3A[j], 0,0,0);
          a3B[j] = __builtin_amdgcn_mfma_f32_16x16x32_bf16(w3f[0][nt], hB0, a3B[j], 0,0,0);
        }
        #pragma unroll
        for (int j = 0; j < 4; ++j) {
          const int nt = half*4 + j;
          a3A[j] = __builtin_amdgcn_mfma_f32_16x16x32_bf16(w3f[1][nt], hA1, a3A[j], 0,0,0);
          a3B[j] = __builtin_amdgcn_mfma_f32_16x16x32_bf16(w3f[1][nt], hB1, a3B[j], 0,0,0);
        }
        #pragma unroll
        for (int j = 0; j < 4; ++j) {
          const int nt = half*4 + j;
          #pragma unroll
          for (int r = 0; r < 4; ++r)
            runmax[nt][r] = fmaxf(runmax[nt][r],
                                  fmaxf(a3A[j][r] + vmA, a3B[j][r] + vmB));
        }
      }
    }

    pA2 = pA3; pB2 = pB3;
  }

  // ---- phase 3: reduce over points, +b3, relu, store ----
  #pragma unroll
  for (int nt = 0; nt < 8; ++nt) {
    #pragma unroll
    for (int r = 0; r < 4; ++r) {
      float m = runmax[nt][r];
      m = fmaxf(m, __shfl_xor(m, 1));
      m = fmaxf(m, __shfl_xor(m, 2));
      m = fmaxf(m, __shfl_xor(m, 4));
      m = fmaxf(m, __shfl_xor(m, 8));
      runmax[nt][r] = m;
    }
    if (cl == 0) *(f32x4*)(sMax + w*128 + nt*16 + q*4) = runmax[nt];
  }
  __syncthreads();
  if (tid < 128) {
    float m = fmaxf(fmaxf(sMax[tid], sMax[128+tid]),
                    fmaxf(sMax[256+tid], sMax[384+tid]));
    outF[k*128 + tid] = fmaxf(m + sB3[tid], 0.f);
  }
}

// ---------------------------------------------------------------- launch
extern "C" void kernel_launch(void* const* d_in, const int* in_sizes, int n_in,
                              void* d_out, int out_size, void* d_ws, size_t ws_size,
                              hipStream_t stream) {
  const float* coords   = (const float*)d_in[0];
  const float* features = (const float*)d_in[1];
  const int*   cidx     = (const int*)d_in[2];
  const float* W1 = (const float*)d_in[3];
  const float* b1 = (const float*)d_in[4];
  const float* W2 = (const float*)d_in[5];
  const float* b2 = (const float*)d_in[6];
  const float* W3 = (const float*)d_in[7];
  const float* b3 = (const float*)d_in[8];
  float* out = (float*)d_out;           // [0:3072) cent, [3072:) new_features

  char* ws = (char*)d_ws;
  u64* maskbuf        = (u64*)(ws + 0);                      // 13,107,200
  unsigned short* uBF = (unsigned short*)(ws + 13107200);    // 12,800,000
  f32x4* coords4      = (f32x4*)(ws + 25907200);             //  1,600,000
  unsigned short* W2T = (unsigned short*)(ws + 27507200);    //      9,216
  unsigned short* W3T = (unsigned short*)(ws + 27516416);    //     18,432

  // flat tail items: 100000 + 4608 + 9216 + 1024 = 114848 -> 449 blocks
  build_prep_kernel<<<MB_BLKS + UG_BLKS + 449, 256, 0, stream>>>(
      coords, features, cidx, W1, b1, W2, W3,
      maskbuf, uBF, coords4, W2T, W3T, out);
  fused_kernel<<<KCENT, 256, 0, stream>>>(
      maskbuf, uBF, coords4, out, W1, b2, b3,
      W2T, W3T, out + 3072);
}